// Round 1
// baseline (2104.640 us; speedup 1.0000x reference)
//
#include <hip/hip_runtime.h>
#include <hip/hip_bf16.h>
#include <math.h>

// DiT attention block, fp32 baseline.
// B=4 L=2048 D=1024 H=16 HD=64.
// ws layout: qbuf | kbuf | vbuf (each B*H*L*HD fp32, BHLD layout) | obuf (B*L*D fp32)
// ws needed: 4 * 8388608 * 4 B = 128 MiB.

#define NB 4
#define NL 2048
#define ND 1024
#define NH 16
#define NHD 64

static constexpr int GM = NB * NL;  // 8192 rows

// ---------------------------------------------------------------------------
// fp32 GEMM: out = A[GM][1024] @ W[1024][N] + bias
// 128x128 tile, BK=16, 256 threads, 8x8 per thread (classic SGEMM).
// MODE 0: plain row-major write. MODE 1: split-QKV write into (3,B,H,L,HD).
// ---------------------------------------------------------------------------
template <int N, int MODE>
__global__ __launch_bounds__(256, 2) void gemm_f32(
    const float* __restrict__ A, const float* __restrict__ W,
    const float* __restrict__ bias, float* __restrict__ out) {
  constexpr int K = ND;
  __shared__ float As[16][132];  // transposed A tile: As[k][m]
  __shared__ float Bs[16][132];
  const int tid = threadIdx.x;
  const int tx = tid & 15, ty = tid >> 4;
  const int m0 = blockIdx.y * 128;
  const int n0 = blockIdx.x * 128;

  float acc[8][8] = {};

  for (int k0 = 0; k0 < K; k0 += 16) {
#pragma unroll
    for (int i = 0; i < 2; ++i) {  // A tile 128x16, float4 along k, transpose
      const int f = tid + i * 256;
      const int row = f >> 2;
      const int kq = (f & 3) << 2;
      const float4 v = *(const float4*)&A[(size_t)(m0 + row) * K + k0 + kq];
      As[kq + 0][row] = v.x;
      As[kq + 1][row] = v.y;
      As[kq + 2][row] = v.z;
      As[kq + 3][row] = v.w;
    }
#pragma unroll
    for (int i = 0; i < 2; ++i) {  // B tile 16x128, float4 along n
      const int f = tid + i * 256;
      const int row = f >> 5;
      const int nq = (f & 31) << 2;
      *(float4*)&Bs[row][nq] = *(const float4*)&W[(size_t)(k0 + row) * N + n0 + nq];
    }
    __syncthreads();
#pragma unroll
    for (int kk = 0; kk < 16; ++kk) {
      float a[8], b[8];
      *(float4*)&a[0] = *(float4*)&As[kk][ty * 4];
      *(float4*)&a[4] = *(float4*)&As[kk][ty * 4 + 64];
      *(float4*)&b[0] = *(float4*)&Bs[kk][tx * 4];
      *(float4*)&b[4] = *(float4*)&Bs[kk][tx * 4 + 64];
#pragma unroll
      for (int i = 0; i < 8; ++i)
#pragma unroll
        for (int j = 0; j < 8; ++j) acc[i][j] = fmaf(a[i], b[j], acc[i][j]);
    }
    __syncthreads();
  }

#pragma unroll
  for (int i = 0; i < 8; ++i) {
    const int m = m0 + ty * 4 + (i & 3) + ((i & 4) << 4);  // +64 when i>=4
#pragma unroll
    for (int jh = 0; jh < 2; ++jh) {
      const int n = n0 + tx * 4 + jh * 64;
      const float4 bv = *(const float4*)&bias[n];
      float4 v;
      v.x = acc[i][jh * 4 + 0] + bv.x;
      v.y = acc[i][jh * 4 + 1] + bv.y;
      v.z = acc[i][jh * 4 + 2] + bv.z;
      v.w = acc[i][jh * 4 + 3] + bv.w;
      if (MODE == 0) {
        *(float4*)&out[(size_t)m * N + n] = v;
      } else {
        // n -> (s, h, hd); m -> (b, l). dst: s-th buffer, (B,H,L,HD) layout.
        const int s = n >> 10;
        const int h = (n >> 6) & (NH - 1);
        const int hd = n & (NHD - 1);
        const int b = m >> 11;
        const int l = m & (NL - 1);
        float* dst = out + (size_t)s * ((size_t)NB * NH * NL * NHD) +
                     ((((size_t)b * NH + h) * NL + l) * NHD + hd);
        *(float4*)dst = v;
      }
    }
  }
}

// ---------------------------------------------------------------------------
// RMSNorm(q|k over HD) + RoPE, in place on (B,H,L,HD) buffers. Wave per row.
// Folds attention scale 1/8 (exact) into q.
// ---------------------------------------------------------------------------
__global__ __launch_bounds__(256) void rms_rope(float* __restrict__ q,
                                                float* __restrict__ k,
                                                const float* __restrict__ qw,
                                                const float* __restrict__ kw) {
  const int row = blockIdx.x * 4 + (threadIdx.x >> 6);
  const int lane = threadIdx.x & 63;
  const int l = row & (NL - 1);
  const size_t idx = (size_t)row * NHD + lane;
  float qv = q[idx], kv = k[idx];
  float qs = qv * qv, ks = kv * kv;
#pragma unroll
  for (int m = 32; m; m >>= 1) {
    qs += __shfl_xor(qs, m);
    ks += __shfl_xor(ks, m);
  }
  const float qr = rsqrtf(qs * (1.0f / 64.0f) + 1e-6f);
  const float kr = rsqrtf(ks * (1.0f / 64.0f) + 1e-6f);
  qv *= qr * qw[lane];
  kv *= kr * kw[lane];
  // rope: pair lane d with lane d^32; angle from i = d & 31
  const int i = lane & 31;
  const float invf = 1.0f / powf(10000.0f, (float)(2 * i) * (1.0f / 64.0f));
  const float ang = (float)l * invf;
  float sn, cs;
  sincosf(ang, &sn, &cs);
  const float qo = __shfl_xor(qv, 32);
  const float ko = __shfl_xor(kv, 32);
  const float sgn = (lane < 32) ? -sn : sn;
  q[idx] = (qv * cs + qo * sgn) * 0.125f;  // fold HD^-0.5 into q (exact)
  k[idx] = kv * cs + ko * sgn;
}

// ---------------------------------------------------------------------------
// Flash attention fp32. Per block: one (b,h), 64 Q rows; loop 64-row KV tiles.
// 256 threads. Thread (g=tid>>4, c=tid&15) owns S rows {g+16i}, S cols {c+16j},
// O cols {c*4+j}. LDS: 4 x [64][16] float4 = exactly 64 KiB, XOR-swizzled
// (phys f4 col = logical f4 ^ (row&7)) so stride-64 row reads don't bank-clash.
// ---------------------------------------------------------------------------
__global__ __launch_bounds__(256, 2) void flash_attn(
    const float* __restrict__ q, const float* __restrict__ k,
    const float* __restrict__ v, float* __restrict__ o) {
  __shared__ float4 Qs[64][16];
  __shared__ float4 Ks[64][16];
  __shared__ float4 Vs[64][16];
  __shared__ float4 Ps[64][16];
  const int tid = threadIdx.x;
  const int c = tid & 15;
  const int g = tid >> 4;
  const int bh = blockIdx.y;
  const int q0 = blockIdx.x * 64;

  const float* qbase = q + ((size_t)bh * NL + q0) * NHD;
#pragma unroll
  for (int i = 0; i < 4; ++i) {
    const int n = tid + i * 256;  // float4 linear index over 64x64 tile
    const int row = n >> 4, f4 = n & 15;
    Qs[row][f4 ^ (row & 7)] = *(const float4*)&qbase[n * 4];
  }

  float om[4], ol[4], oa[4][4];
#pragma unroll
  for (int i = 0; i < 4; ++i) {
    om[i] = -INFINITY;
    ol[i] = 0.0f;
#pragma unroll
    for (int j = 0; j < 4; ++j) oa[i][j] = 0.0f;
  }

  for (int kt = 0; kt < NL / 64; ++kt) {
    const float* kbase = k + ((size_t)bh * NL + kt * 64) * NHD;
    const float* vbase = v + ((size_t)bh * NL + kt * 64) * NHD;
#pragma unroll
    for (int i = 0; i < 4; ++i) {
      const int n = tid + i * 256;
      const int row = n >> 4, f4 = n & 15;
      Ks[row][f4 ^ (row & 7)] = *(const float4*)&kbase[n * 4];
      Vs[row][f4 ^ (row & 7)] = *(const float4*)&vbase[n * 4];
    }
    __syncthreads();

    // S = (Q*scale) K^T for this tile
    float s[4][4];
#pragma unroll
    for (int i = 0; i < 4; ++i)
#pragma unroll
      for (int j = 0; j < 4; ++j) s[i][j] = 0.0f;
#pragma unroll
    for (int d4 = 0; d4 < 16; ++d4) {
      float4 qa[4], kb[4];
#pragma unroll
      for (int i = 0; i < 4; ++i) qa[i] = Qs[g + 16 * i][d4 ^ (g & 7)];
#pragma unroll
      for (int j = 0; j < 4; ++j) kb[j] = Ks[c + 16 * j][d4 ^ (c & 7)];
#pragma unroll
      for (int i = 0; i < 4; ++i)
#pragma unroll
        for (int j = 0; j < 4; ++j) {
          s[i][j] = fmaf(qa[i].x, kb[j].x, s[i][j]);
          s[i][j] = fmaf(qa[i].y, kb[j].y, s[i][j]);
          s[i][j] = fmaf(qa[i].z, kb[j].z, s[i][j]);
          s[i][j] = fmaf(qa[i].w, kb[j].w, s[i][j]);
        }
    }

    // online softmax; P into LDS
#pragma unroll
    for (int i = 0; i < 4; ++i) {
      float pm = fmaxf(fmaxf(s[i][0], s[i][1]), fmaxf(s[i][2], s[i][3]));
#pragma unroll
      for (int msk = 8; msk; msk >>= 1) pm = fmaxf(pm, __shfl_xor(pm, msk));
      const float mnew = fmaxf(om[i], pm);
      const float alpha = __expf(om[i] - mnew);
      om[i] = mnew;
      float p[4], rs = 0.0f;
#pragma unroll
      for (int j = 0; j < 4; ++j) {
        p[j] = __expf(s[i][j] - mnew);
        rs += p[j];
      }
#pragma unroll
      for (int msk = 8; msk; msk >>= 1) rs += __shfl_xor(rs, msk);
      ol[i] = ol[i] * alpha + rs;
#pragma unroll
      for (int j = 0; j < 4; ++j) oa[i][j] *= alpha;
      const int r = g + 16 * i;
#pragma unroll
      for (int j = 0; j < 4; ++j) {
        const int colf4 = (c >> 2) + 4 * j;  // logical float4 col of c+16j
        float* pp = (float*)&Ps[r][colf4 ^ (g & 7)];
        pp[c & 3] = p[j];
      }
    }
    __syncthreads();

    // O += P V
#pragma unroll
    for (int k4 = 0; k4 < 16; ++k4) {
      float pav[4][4];
#pragma unroll
      for (int i = 0; i < 4; ++i) {
        const float4 t = Ps[g + 16 * i][k4 ^ (g & 7)];
        pav[i][0] = t.x;
        pav[i][1] = t.y;
        pav[i][2] = t.z;
        pav[i][3] = t.w;
      }
#pragma unroll
      for (int kk = 0; kk < 4; ++kk) {
        const int kr = k4 * 4 + kk;
        const float4 vb = Vs[kr][c ^ (kr & 7)];
#pragma unroll
        for (int i = 0; i < 4; ++i) {
          oa[i][0] = fmaf(pav[i][kk], vb.x, oa[i][0]);
          oa[i][1] = fmaf(pav[i][kk], vb.y, oa[i][1]);
          oa[i][2] = fmaf(pav[i][kk], vb.z, oa[i][2]);
          oa[i][3] = fmaf(pav[i][kk], vb.w, oa[i][3]);
        }
      }
    }
    __syncthreads();
  }

  // write O (B,L,D) layout so out-proj GEMM reads row-major
  const int b = bh >> 4;
  const int h = bh & (NH - 1);
#pragma unroll
  for (int i = 0; i < 4; ++i) {
    const float inv = 1.0f / ol[i];
    float4 v4;
    v4.x = oa[i][0] * inv;
    v4.y = oa[i][1] * inv;
    v4.z = oa[i][2] * inv;
    v4.w = oa[i][3] * inv;
    const size_t row = (size_t)b * NL + q0 + g + 16 * i;
    *(float4*)&o[row * ND + h * 64 + c * 4] = v4;
  }
}

// ---------------------------------------------------------------------------
extern "C" void kernel_launch(void* const* d_in, const int* in_sizes, int n_in,
                              void* d_out, int out_size, void* d_ws,
                              size_t ws_size, hipStream_t stream) {
  const float* x = (const float*)d_in[0];
  const float* Wqkv = (const float*)d_in[1];
  const float* bqkv = (const float*)d_in[2];
  const float* qn_w = (const float*)d_in[3];
  const float* kn_w = (const float*)d_in[4];
  const float* Wout = (const float*)d_in[5];
  const float* bout = (const float*)d_in[6];
  float* out = (float*)d_out;
  float* ws = (float*)d_ws;

  const size_t S = (size_t)NB * NH * NL * NHD;  // 8388608 floats
  float* qbuf = ws;
  float* kbuf = ws + S;
  float* vbuf = ws + 2 * S;
  float* obuf = ws + 3 * S;  // total 128 MiB of ws

  // 1) QKV projection, epilogue scatters into (B,H,L,HD) q/k/v buffers
  gemm_f32<3 * ND, 1>
      <<<dim3(3 * ND / 128, GM / 128), 256, 0, stream>>>(x, Wqkv, bqkv, qbuf);
  // 2) RMSNorm + RoPE in place on q,k (scale folded into q)
  rms_rope<<<NB * NH * NL / 4, 256, 0, stream>>>(qbuf, kbuf, qn_w, kn_w);
  // 3) flash attention -> obuf in (B,L,D) layout
  flash_attn<<<dim3(NL / 64, NB * NH), 256, 0, stream>>>(qbuf, kbuf, vbuf,
                                                         obuf);
  // 4) output projection
  gemm_f32<ND, 0>
      <<<dim3(ND / 128, GM / 128), 256, 0, stream>>>(obuf, Wout, bout, out);
}

// Round 2
// 684.060 us; speedup vs baseline: 3.0767x; 3.0767x over previous
//
#include <hip/hip_runtime.h>
#include <hip/hip_bf16.h>
#include <math.h>

// DiT attention block — f16-split (hi+lo) MFMA pipeline.
// B=4 L=2048 D=1024 H=16 HD=64.

#define NB 4
#define NL 2048
#define ND 1024
#define NH 16
#define NHD 64
#define GM (NB * NL)  // 8192

typedef _Float16 f16;
typedef _Float16 half4v __attribute__((ext_vector_type(4)));
typedef _Float16 half8v __attribute__((ext_vector_type(8)));
typedef float f32x4 __attribute__((ext_vector_type(4)));

#define MFMA16(a, b, c) __builtin_amdgcn_mfma_f32_16x16x32_f16((a), (b), (c), 0, 0, 0)

__device__ __forceinline__ void gload16(const void* g, void* l) {
  __builtin_amdgcn_global_load_lds((const __attribute__((address_space(1))) void*)g,
                                   (__attribute__((address_space(3))) void*)l, 16, 0, 0);
}

// ---------------------------------------------------------------------------
// cos/sin table for RoPE: tbl[0..65535]=cos(l*invf(i)), tbl[65536..]=sin
// ---------------------------------------------------------------------------
__global__ __launch_bounds__(256) void sctable(float* __restrict__ tbl) {
  const int idx = blockIdx.x * 256 + threadIdx.x;  // 65536 = 2048*32
  const int l = idx >> 5, i = idx & 31;
  const float invf = exp2f(-(float)i * 0.41524101186092029f);  // (2/64)*log2(1e4)
  const float ang = (float)l * invf;
  tbl[idx] = cosf(ang);
  tbl[65536 + idx] = sinf(ang);
}

// ---------------------------------------------------------------------------
// transpose + f16 hi/lo split: W[1024][N] fp32 -> Th/Tl [N][1024] f16
// ---------------------------------------------------------------------------
__global__ __launch_bounds__(256) void transplit(const float* __restrict__ Wsrc,
                                                 f16* __restrict__ Th,
                                                 f16* __restrict__ Tl, int N) {
  __shared__ float t[64][65];
  const int tid = threadIdx.x;
  const int n0 = blockIdx.x * 64, k0 = blockIdx.y * 64;
#pragma unroll
  for (int it = 0; it < 4; ++it) {
    const int e = it * 256 + tid;
    const int r = e >> 4, c4 = (e & 15) << 2;
    const float4 v = *(const float4*)&Wsrc[(size_t)(k0 + r) * N + n0 + c4];
    t[r][c4] = v.x; t[r][c4 + 1] = v.y; t[r][c4 + 2] = v.z; t[r][c4 + 3] = v.w;
  }
  __syncthreads();
#pragma unroll
  for (int it = 0; it < 4; ++it) {
    const int e = it * 256 + tid;
    const int rn = e >> 4, ck = (e & 15) << 2;
    half4v h, lo;
#pragma unroll
    for (int u = 0; u < 4; ++u) {
      const float v = t[ck + u][rn];
      const f16 hv = (f16)v;
      h[u] = hv;
      lo[u] = (f16)(v - (float)hv);
    }
    *(half4v*)&Th[(size_t)(n0 + rn) * 1024 + k0 + ck] = h;
    *(half4v*)&Tl[(size_t)(n0 + rn) * 1024 + k0 + ck] = lo;
  }
}

// ---------------------------------------------------------------------------
// Split-f16 GEMM: C = A[GM][1024] @ B^T[N][1024]^T + bias, via
// Ah*Bh + Ah*Bl + Al*Bh (16x16x32 f16 MFMA). 128x128 tile, BK=32, 4 waves.
// ASRC=0: A fp32, reg-staged + split on the fly. ASRC=1: A pre-split f16.
// MODE=0: plain fp32 store. MODE=1: QKV epilogue (bias->rms->rope->split).
// ---------------------------------------------------------------------------
template <int N, int ASRC, int MODE>
__global__ __launch_bounds__(256) void gemm_split(
    const float* __restrict__ A32, const f16* __restrict__ Ah_g,
    const f16* __restrict__ Al_g, const f16* __restrict__ Bh_g,
    const f16* __restrict__ Bl_g, const float* __restrict__ bias,
    float* __restrict__ out32, f16* __restrict__ qh, f16* __restrict__ ql,
    f16* __restrict__ kh, f16* __restrict__ kl, f16* __restrict__ vth,
    const float* __restrict__ qw, const float* __restrict__ kw,
    const float* __restrict__ tbl) {
  __shared__ f16 Ah[4096], Al[4096], Bh[4096], Bl[4096];
  const int tid = threadIdx.x;
  const int ln = tid & 63, wv = tid >> 6;
  const int ln15 = ln & 15, q4 = ln >> 4;

  // XCD-aware bijective swizzle (nwg % 8 == 0)
  const int nwg = (N / 128) * (GM / 128);
  const int flat = blockIdx.y * gridDim.x + blockIdx.x;
  const int sw = (flat & 7) * (nwg >> 3) + (flat >> 3);
  const int bx = sw % (N / 128), by = sw / (N / 128);
  const int m0 = by * 128, n0 = bx * 128;
  const int wr = wv >> 1, wc = wv & 1;

  f32x4 acc[4][4];
#pragma unroll
  for (int i = 0; i < 4; ++i)
#pragma unroll
    for (int j = 0; j < 4; ++j) acc[i][j] = (f32x4){0.f, 0.f, 0.f, 0.f};

  for (int k0 = 0; k0 < 1024; k0 += 32) {
    if constexpr (ASRC == 0) {
      // A: fp32 global -> split -> LDS (fragment-ordered)
#pragma unroll
      for (int it = 0; it < 4; ++it) {
        const int e = it * 256 + tid;
        const int row = e >> 3, kq = (e & 7) << 2;
        const float4 v = *(const float4*)&A32[(size_t)(m0 + row) * 1024 + k0 + kq];
        half4v h, lo;
        h[0] = (f16)v.x; lo[0] = (f16)(v.x - (float)h[0]);
        h[1] = (f16)v.y; lo[1] = (f16)(v.y - (float)h[1]);
        h[2] = (f16)v.z; lo[2] = (f16)(v.z - (float)h[2]);
        h[3] = (f16)v.w; lo[3] = (f16)(v.w - (float)h[3]);
        const int idx = ((row >> 4) << 9) + (((row & 15) + ((kq >> 3) << 4)) << 3) + (kq & 7);
        *(half4v*)&Ah[idx] = h;
        *(half4v*)&Al[idx] = lo;
      }
      // B: pre-split, async frag-ordered loads (2 frags/wave x {h,l})
#pragma unroll
      for (int t = 0; t < 2; ++t) {
        const int f = wv * 2 + t;
        const size_t off = (size_t)(n0 + f * 16 + ln15) * 1024 + k0 + q4 * 8;
        gload16(Bh_g + off, &Bh[f * 512]);
        gload16(Bl_g + off, &Bl[f * 512]);
      }
    } else {
#pragma unroll
      for (int t = 0; t < 2; ++t) {
        const int f = wv * 2 + t;
        const size_t aoff = (size_t)(m0 + f * 16 + ln15) * 1024 + k0 + q4 * 8;
        const size_t boff = (size_t)(n0 + f * 16 + ln15) * 1024 + k0 + q4 * 8;
        gload16(Ah_g + aoff, &Ah[f * 512]);
        gload16(Al_g + aoff, &Al[f * 512]);
        gload16(Bh_g + boff, &Bh[f * 512]);
        gload16(Bl_g + boff, &Bl[f * 512]);
      }
    }
    __syncthreads();

    half8v a_h[4], a_l[4];
#pragma unroll
    for (int i = 0; i < 4; ++i) {
      a_h[i] = *(half8v*)&Ah[(wr * 4 + i) * 512 + ln * 8];
      a_l[i] = *(half8v*)&Al[(wr * 4 + i) * 512 + ln * 8];
    }
#pragma unroll
    for (int j = 0; j < 4; ++j) {
      const half8v b_h = *(half8v*)&Bh[(wc * 4 + j) * 512 + ln * 8];
      const half8v b_l = *(half8v*)&Bl[(wc * 4 + j) * 512 + ln * 8];
#pragma unroll
      for (int i = 0; i < 4; ++i) {
        acc[i][j] = MFMA16(a_h[i], b_h, acc[i][j]);
        acc[i][j] = MFMA16(a_l[i], b_h, acc[i][j]);
        acc[i][j] = MFMA16(a_h[i], b_l, acc[i][j]);
      }
    }
    __syncthreads();
  }

  // ---------------- epilogue ----------------
  const int nc = n0 + wc * 64;
  float bv[4];
#pragma unroll
  for (int j = 0; j < 4; ++j) bv[j] = bias[nc + j * 16 + ln15];

  if constexpr (MODE == 0) {
#pragma unroll
    for (int i = 0; i < 4; ++i) {
      const int m = m0 + wr * 64 + i * 16 + q4 * 4;
#pragma unroll
      for (int j = 0; j < 4; ++j)
#pragma unroll
        for (int r = 0; r < 4; ++r)
          out32[(size_t)(m + r) * N + nc + j * 16 + ln15] = acc[i][j][r] + bv[j];
    }
  } else {
    const int s = nc >> 10;          // 0=q 1=k 2=v
    const int h = (nc >> 6) & 15;    // head
    if (s == 2) {
      // V: split not needed -> plain f16, transposed [B,H,HD,L]
#pragma unroll
      for (int i = 0; i < 4; ++i) {
        const int m = m0 + wr * 64 + i * 16 + q4 * 4;
        const int b = m >> 11, l0 = m & (NL - 1);
#pragma unroll
        for (int j = 0; j < 4; ++j) {
          half4v pv;
#pragma unroll
          for (int r = 0; r < 4; ++r) pv[r] = (f16)(acc[i][j][r] + bv[j]);
          *(half4v*)&vth[(size_t)((b * NH + h) * NHD + j * 16 + ln15) * NL + l0] = pv;
        }
      }
    } else {
      const float* nw = (s == 0) ? qw : kw;
      f16* dh = (s == 0) ? qh : kh;
      f16* dl = (s == 0) ? ql : kl;
      // fold attention scale 1/8 and log2(e) into q
      const float qsc = (s == 0) ? 0.125f * 1.4426950408889634f : 1.0f;
      float wn[4];
#pragma unroll
      for (int j = 0; j < 4; ++j) wn[j] = nw[j * 16 + ln15];
#pragma unroll
      for (int i = 0; i < 4; ++i) {
        const int m = m0 + wr * 64 + i * 16 + q4 * 4;
        const int b = m >> 11, l0 = m & (NL - 1);
        float vv[4][4];
        float ss[4] = {0.f, 0.f, 0.f, 0.f};
#pragma unroll
        for (int j = 0; j < 4; ++j)
#pragma unroll
          for (int r = 0; r < 4; ++r) {
            vv[j][r] = acc[i][j][r] + bv[j];
            ss[r] += vv[j][r] * vv[j][r];
          }
#pragma unroll
        for (int r = 0; r < 4; ++r) {
          ss[r] += __shfl_xor(ss[r], 1);
          ss[r] += __shfl_xor(ss[r], 2);
          ss[r] += __shfl_xor(ss[r], 4);
          ss[r] += __shfl_xor(ss[r], 8);
          ss[r] = rsqrtf(ss[r] * (1.0f / 64.0f) + 1e-6f);
        }
#pragma unroll
        for (int j = 0; j < 4; ++j)
#pragma unroll
          for (int r = 0; r < 4; ++r) vv[j][r] *= ss[r] * wn[j];
        // rope: pair (hd, hd+32) = (j, j+2), angle index = jj*16+ln15
#pragma unroll
        for (int jj = 0; jj < 2; ++jj)
#pragma unroll
          for (int r = 0; r < 4; ++r) {
            const int l = l0 + r;
            const float c = tbl[l * 32 + jj * 16 + ln15];
            const float sn = tbl[65536 + l * 32 + jj * 16 + ln15];
            const float t1 = vv[jj][r], t2 = vv[jj + 2][r];
            vv[jj][r] = t1 * c - t2 * sn;
            vv[jj + 2][r] = t1 * sn + t2 * c;
          }
#pragma unroll
        for (int j = 0; j < 4; ++j)
#pragma unroll
          for (int r = 0; r < 4; ++r) {
            const float val = vv[j][r] * qsc;
            const f16 hv = (f16)val;
            const size_t di = (size_t)((b * NH + h) * NL + l0 + r) * NHD + j * 16 + ln15;
            dh[di] = hv;
            dl[di] = (f16)(val - (float)hv);
          }
      }
    }
  }
}

// ---------------------------------------------------------------------------
// Flash attention, f16-split QK^T (3 MFMA), plain-f16 PV. Q-tile 128 (4 waves
// x 32 rows), KV-tile 64. Softmax in log2 domain (scale*log2e folded into q).
// Writes O pre-split (hi/lo f16) in [B*L][D] layout for the out-proj GEMM.
// ---------------------------------------------------------------------------
__global__ __launch_bounds__(256) void flash_mfma(
    const f16* __restrict__ qh, const f16* __restrict__ ql,
    const f16* __restrict__ kh, const f16* __restrict__ kl,
    const f16* __restrict__ vth, f16* __restrict__ Oh, f16* __restrict__ Ol) {
  __shared__ f16 KH[4096], KL[4096], VT[4096];
  __shared__ f16 P[4][32][72];  // row stride 144 B (16-B aligned)
  const int tid = threadIdx.x;
  const int ln = tid & 63, wv = tid >> 6;
  const int ln15 = ln & 15, q4 = ln >> 4;

  // head-major XCD swizzle: each XCD gets 8 whole heads
  const int flat = blockIdx.x;  // 1024
  const int swz = (flat & 7) * 128 + (flat >> 3);
  const int head = swz >> 4;  // b*16+h
  const int qt = swz & 15;
  const int b = head >> 4, h = head & 15;
  const int q0 = qt * 128 + wv * 32;
  const size_t hbase = (size_t)head * NL * NHD;

  half8v qfh[2][2], qfl[2][2];
#pragma unroll
  for (int rf = 0; rf < 2; ++rf)
#pragma unroll
    for (int kb = 0; kb < 2; ++kb) {
      const size_t off = hbase + (size_t)(q0 + rf * 16 + ln15) * NHD + kb * 32 + q4 * 8;
      qfh[rf][kb] = *(const half8v*)&qh[off];
      qfl[rf][kb] = *(const half8v*)&ql[off];
    }

  f32x4 o_[2][4];
  float m_[2][4], l_[2][4];
#pragma unroll
  for (int rf = 0; rf < 2; ++rf)
#pragma unroll
    for (int cf = 0; cf < 4; ++cf) o_[rf][cf] = (f32x4){0.f, 0.f, 0.f, 0.f};
#pragma unroll
  for (int rf = 0; rf < 2; ++rf)
#pragma unroll
    for (int r = 0; r < 4; ++r) {
      m_[rf][r] = -INFINITY;
      l_[rf][r] = 0.f;
    }

  for (int kt = 0; kt < NL / 64; ++kt) {
    const int kv0 = kt * 64;
    // stage K hi/lo + V^T: 24 frags, 6 per wave
#pragma unroll
    for (int t = 0; t < 6; ++t) {
      const int f = wv * 6 + t;
      if (f < 8) {
        gload16(kh + hbase + (size_t)(kv0 + (f >> 1) * 16 + ln15) * NHD + (f & 1) * 32 + q4 * 8,
                &KH[f * 512]);
      } else if (f < 16) {
        const int g = f - 8;
        gload16(kl + hbase + (size_t)(kv0 + (g >> 1) * 16 + ln15) * NHD + (g & 1) * 32 + q4 * 8,
                &KL[g * 512]);
      } else {
        const int g = f - 16;
        gload16(vth + (size_t)(head * NHD + (g >> 1) * 16 + ln15) * NL + kv0 + (g & 1) * 32 + q4 * 8,
                &VT[g * 512]);
      }
    }
    __syncthreads();

    // S = Qh*Kh + Ql*Kh + Qh*Kl
    f32x4 s_[2][4];
#pragma unroll
    for (int rf = 0; rf < 2; ++rf)
#pragma unroll
      for (int cb = 0; cb < 4; ++cb) s_[rf][cb] = (f32x4){0.f, 0.f, 0.f, 0.f};
#pragma unroll
    for (int cb = 0; cb < 4; ++cb) {
      const half8v kh0 = *(half8v*)&KH[(cb * 2 + 0) * 512 + ln * 8];
      const half8v kh1 = *(half8v*)&KH[(cb * 2 + 1) * 512 + ln * 8];
      const half8v kl0 = *(half8v*)&KL[(cb * 2 + 0) * 512 + ln * 8];
      const half8v kl1 = *(half8v*)&KL[(cb * 2 + 1) * 512 + ln * 8];
#pragma unroll
      for (int rf = 0; rf < 2; ++rf) {
        f32x4 t = s_[rf][cb];
        t = MFMA16(qfh[rf][0], kh0, t);
        t = MFMA16(qfh[rf][1], kh1, t);
        t = MFMA16(qfl[rf][0], kh0, t);
        t = MFMA16(qfl[rf][1], kh1, t);
        t = MFMA16(qfh[rf][0], kl0, t);
        t = MFMA16(qfh[rf][1], kl1, t);
        s_[rf][cb] = t;
      }
    }

    // online softmax (log2 domain), P -> LDS (per-wave private)
#pragma unroll
    for (int rf = 0; rf < 2; ++rf) {
      float al[4];
#pragma unroll
      for (int r = 0; r < 4; ++r) {
        float pm = fmaxf(fmaxf(s_[rf][0][r], s_[rf][1][r]),
                         fmaxf(s_[rf][2][r], s_[rf][3][r]));
        pm = fmaxf(pm, __shfl_xor(pm, 1));
        pm = fmaxf(pm, __shfl_xor(pm, 2));
        pm = fmaxf(pm, __shfl_xor(pm, 4));
        pm = fmaxf(pm, __shfl_xor(pm, 8));
        const float mn = fmaxf(m_[rf][r], pm);
        al[r] = exp2f(m_[rf][r] - mn);
        m_[rf][r] = mn;
      }
      float rs[4] = {0.f, 0.f, 0.f, 0.f};
#pragma unroll
      for (int cb = 0; cb < 4; ++cb)
#pragma unroll
        for (int r = 0; r < 4; ++r) {
          const float p = exp2f(s_[rf][cb][r] - m_[rf][r]);
          rs[r] += p;
          P[wv][rf * 16 + q4 * 4 + r][cb * 16 + ln15] = (f16)p;
        }
#pragma unroll
      for (int r = 0; r < 4; ++r) {
        rs[r] += __shfl_xor(rs[r], 1);
        rs[r] += __shfl_xor(rs[r], 2);
        rs[r] += __shfl_xor(rs[r], 4);
        rs[r] += __shfl_xor(rs[r], 8);
        l_[rf][r] = l_[rf][r] * al[r] + rs[r];
      }
#pragma unroll
      for (int cf = 0; cf < 4; ++cf)
#pragma unroll
        for (int r = 0; r < 4; ++r) o_[rf][cf][r] *= al[r];
    }

    // O += P V   (P read back in A-fragment order; same-wave dependency)
#pragma unroll
    for (int kb = 0; kb < 2; ++kb) {
      half8v pa[2];
#pragma unroll
      for (int rf = 0; rf < 2; ++rf)
        pa[rf] = *(half8v*)&P[wv][rf * 16 + ln15][kb * 32 + q4 * 8];
#pragma unroll
      for (int cf = 0; cf < 4; ++cf) {
        const half8v vb = *(half8v*)&VT[(cf * 2 + kb) * 512 + ln * 8];
#pragma unroll
        for (int rf = 0; rf < 2; ++rf) o_[rf][cf] = MFMA16(pa[rf], vb, o_[rf][cf]);
      }
    }
    __syncthreads();
  }

  // epilogue: normalize, split, write [B*L][D]
  float inv[2][4];
#pragma unroll
  for (int rf = 0; rf < 2; ++rf)
#pragma unroll
    for (int r = 0; r < 4; ++r) inv[rf][r] = 1.0f / l_[rf][r];
#pragma unroll
  for (int rf = 0; rf < 2; ++rf)
#pragma unroll
    for (int cf = 0; cf < 4; ++cf) {
      const int q = q0 + rf * 16 + q4 * 4;
#pragma unroll
      for (int r = 0; r < 4; ++r) {
        const float val = o_[rf][cf][r] * inv[rf][r];
        const f16 hv = (f16)val;
        const size_t di = (size_t)(b * NL + q + r) * ND + h * 64 + cf * 16 + ln15;
        Oh[di] = hv;
        Ol[di] = (f16)(val - (float)hv);
      }
    }
}

// ---------------------------------------------------------------------------
extern "C" void kernel_launch(void* const* d_in, const int* in_sizes, int n_in,
                              void* d_out, int out_size, void* d_ws,
                              size_t ws_size, hipStream_t stream) {
  const float* x = (const float*)d_in[0];
  const float* Wqkv = (const float*)d_in[1];
  const float* bqkv = (const float*)d_in[2];
  const float* qn_w = (const float*)d_in[3];
  const float* kn_w = (const float*)d_in[4];
  const float* Wout = (const float*)d_in[5];
  const float* bout = (const float*)d_in[6];
  float* out = (float*)d_out;

  char* wsb = (char*)d_ws;
  // [0,12) WqT h/l (dead after gemm1); [0,32) Oh/Ol reuse; [32,36) WoT h/l;
  // [36,36.5) rope table; [37,117) qh/ql/kh/kl/vth.
  f16* WqTh = (f16*)(wsb);
  f16* WqTl = (f16*)(wsb + (6u << 20));
  f16* Oh = (f16*)(wsb);
  f16* Ol = (f16*)(wsb + (16u << 20));
  f16* WoTh = (f16*)(wsb + (32u << 20));
  f16* WoTl = (f16*)(wsb + (34u << 20));
  float* tbl = (float*)(wsb + (36u << 20));
  f16* qh = (f16*)(wsb + (37u << 20));
  f16* ql = (f16*)(wsb + (53u << 20));
  f16* kh = (f16*)(wsb + (69u << 20));
  f16* kl = (f16*)(wsb + (85u << 20));
  f16* vth = (f16*)(wsb + (101u << 20));

  sctable<<<256, 256, 0, stream>>>(tbl);
  transplit<<<dim3(48, 16), 256, 0, stream>>>(Wqkv, WqTh, WqTl, 3 * ND);
  transplit<<<dim3(16, 16), 256, 0, stream>>>(Wout, WoTh, WoTl, ND);

  gemm_split<3 * ND, 0, 1><<<dim3(24, 64), 256, 0, stream>>>(
      x, nullptr, nullptr, WqTh, WqTl, bqkv, nullptr, qh, ql, kh, kl, vth,
      qn_w, kn_w, tbl);

  flash_mfma<<<1024, 256, 0, stream>>>(qh, ql, kh, kl, vth, Oh, Ol);

  gemm_split<ND, 1, 0><<<dim3(8, 64), 256, 0, stream>>>(
      nullptr, Oh, Ol, WoTh, WoTl, bout, out, nullptr, nullptr, nullptr,
      nullptr, nullptr, nullptr, nullptr, nullptr);
}

// Round 3
// 567.333 us; speedup vs baseline: 3.7097x; 1.2057x over previous
//
#include <hip/hip_runtime.h>
#include <hip/hip_bf16.h>
#include <math.h>

// DiT attention block — f16-split (hi+lo) MFMA pipeline, swapped-QK^T flash.
// B=4 L=2048 D=1024 H=16 HD=64.

#define NB 4
#define NL 2048
#define ND 1024
#define NH 16
#define NHD 64
#define GM (NB * NL)  // 8192

typedef _Float16 f16;
typedef _Float16 half4v __attribute__((ext_vector_type(4)));
typedef _Float16 half8v __attribute__((ext_vector_type(8)));
typedef float f32x4 __attribute__((ext_vector_type(4)));

#define MFMA16(a, b, c) __builtin_amdgcn_mfma_f32_16x16x32_f16((a), (b), (c), 0, 0, 0)

__device__ __forceinline__ void gload16(const void* g, void* l) {
  __builtin_amdgcn_global_load_lds((const __attribute__((address_space(1))) void*)g,
                                   (__attribute__((address_space(3))) void*)l, 16, 0, 0);
}

// ---------------------------------------------------------------------------
// cos/sin table for RoPE: tbl[0..65535]=cos(l*invf(i)), tbl[65536..]=sin
// ---------------------------------------------------------------------------
__global__ __launch_bounds__(256) void sctable(float* __restrict__ tbl) {
  const int idx = blockIdx.x * 256 + threadIdx.x;  // 65536 = 2048*32
  const int l = idx >> 5, i = idx & 31;
  const float invf = exp2f(-(float)i * 0.41524101186092029f);  // (2/64)*log2(1e4)
  const float ang = (float)l * invf;
  tbl[idx] = cosf(ang);
  tbl[65536 + idx] = sinf(ang);
}

// ---------------------------------------------------------------------------
// hi/lo split of x (row-major passthrough)
// ---------------------------------------------------------------------------
__global__ __launch_bounds__(256) void presplit(const float* __restrict__ x,
                                                f16* __restrict__ xh,
                                                f16* __restrict__ xl) {
  const size_t i = ((size_t)blockIdx.x * 256 + threadIdx.x) * 4;
  const float4 v = *(const float4*)&x[i];
  half4v h, lo;
  h[0] = (f16)v.x; lo[0] = (f16)(v.x - (float)h[0]);
  h[1] = (f16)v.y; lo[1] = (f16)(v.y - (float)h[1]);
  h[2] = (f16)v.z; lo[2] = (f16)(v.z - (float)h[2]);
  h[3] = (f16)v.w; lo[3] = (f16)(v.w - (float)h[3]);
  *(half4v*)&xh[i] = h;
  *(half4v*)&xl[i] = lo;
}

// ---------------------------------------------------------------------------
// transpose + f16 hi/lo split: W[1024][N] fp32 -> Th/Tl [N][1024] f16
// ---------------------------------------------------------------------------
__global__ __launch_bounds__(256) void transplit(const float* __restrict__ Wsrc,
                                                 f16* __restrict__ Th,
                                                 f16* __restrict__ Tl, int N) {
  __shared__ float t[64][65];
  const int tid = threadIdx.x;
  const int n0 = blockIdx.x * 64, k0 = blockIdx.y * 64;
#pragma unroll
  for (int it = 0; it < 4; ++it) {
    const int e = it * 256 + tid;
    const int r = e >> 4, c4 = (e & 15) << 2;
    const float4 v = *(const float4*)&Wsrc[(size_t)(k0 + r) * N + n0 + c4];
    t[r][c4] = v.x; t[r][c4 + 1] = v.y; t[r][c4 + 2] = v.z; t[r][c4 + 3] = v.w;
  }
  __syncthreads();
#pragma unroll
  for (int it = 0; it < 4; ++it) {
    const int e = it * 256 + tid;
    const int rn = e >> 4, ck = (e & 15) << 2;
    half4v h, lo;
#pragma unroll
    for (int u = 0; u < 4; ++u) {
      const float v = t[ck + u][rn];
      const f16 hv = (f16)v;
      h[u] = hv;
      lo[u] = (f16)(v - (float)hv);
    }
    *(half4v*)&Th[(size_t)(n0 + rn) * 1024 + k0 + ck] = h;
    *(half4v*)&Tl[(size_t)(n0 + rn) * 1024 + k0 + ck] = lo;
  }
}

// ---------------------------------------------------------------------------
// Split-f16 GEMM: C = A[GM][1024] @ B^T[N][1024]^T + bias, via
// Ah*Bh + Ah*Bl + Al*Bh (16x16x32 f16 MFMA). 128x128 tile, BK=32, 4 waves.
// A and B both pre-split, staged via global_load_lds only.
// MODE=0: plain fp32 store. MODE=1: QKV epilogue (bias->rms->rope->split).
// ---------------------------------------------------------------------------
template <int N, int MODE>
__global__ __launch_bounds__(256) void gemm_split(
    const f16* __restrict__ Ah_g, const f16* __restrict__ Al_g,
    const f16* __restrict__ Bh_g, const f16* __restrict__ Bl_g,
    const float* __restrict__ bias, float* __restrict__ out32,
    f16* __restrict__ qh, f16* __restrict__ ql, f16* __restrict__ kh,
    f16* __restrict__ kl, f16* __restrict__ vth, const float* __restrict__ qw,
    const float* __restrict__ kw, const float* __restrict__ tbl) {
  __shared__ f16 Ah[4096], Al[4096], Bh[4096], Bl[4096];
  const int tid = threadIdx.x;
  const int ln = tid & 63, wv = tid >> 6;
  const int ln15 = ln & 15, q4 = ln >> 4;

  // XCD-aware bijective swizzle (nwg % 8 == 0)
  const int nwg = (N / 128) * (GM / 128);
  const int flat = blockIdx.y * gridDim.x + blockIdx.x;
  const int sw = (flat & 7) * (nwg >> 3) + (flat >> 3);
  const int bx = sw % (N / 128), by = sw / (N / 128);
  const int m0 = by * 128, n0 = bx * 128;
  const int wr = wv >> 1, wc = wv & 1;

  f32x4 acc[4][4];
#pragma unroll
  for (int i = 0; i < 4; ++i)
#pragma unroll
    for (int j = 0; j < 4; ++j) acc[i][j] = (f32x4){0.f, 0.f, 0.f, 0.f};

  for (int k0 = 0; k0 < 1024; k0 += 32) {
#pragma unroll
    for (int t = 0; t < 2; ++t) {
      const int f = wv * 2 + t;
      const size_t aoff = (size_t)(m0 + f * 16 + ln15) * 1024 + k0 + q4 * 8;
      const size_t boff = (size_t)(n0 + f * 16 + ln15) * 1024 + k0 + q4 * 8;
      gload16(Ah_g + aoff, &Ah[f * 512]);
      gload16(Al_g + aoff, &Al[f * 512]);
      gload16(Bh_g + boff, &Bh[f * 512]);
      gload16(Bl_g + boff, &Bl[f * 512]);
    }
    __syncthreads();

    half8v a_h[4], a_l[4];
#pragma unroll
    for (int i = 0; i < 4; ++i) {
      a_h[i] = *(half8v*)&Ah[(wr * 4 + i) * 512 + ln * 8];
      a_l[i] = *(half8v*)&Al[(wr * 4 + i) * 512 + ln * 8];
    }
#pragma unroll
    for (int j = 0; j < 4; ++j) {
      const half8v b_h = *(half8v*)&Bh[(wc * 4 + j) * 512 + ln * 8];
      const half8v b_l = *(half8v*)&Bl[(wc * 4 + j) * 512 + ln * 8];
#pragma unroll
      for (int i = 0; i < 4; ++i) {
        acc[i][j] = MFMA16(a_h[i], b_h, acc[i][j]);
        acc[i][j] = MFMA16(a_l[i], b_h, acc[i][j]);
        acc[i][j] = MFMA16(a_h[i], b_l, acc[i][j]);
      }
    }
    __syncthreads();
  }

  // ---------------- epilogue ----------------
  const int nc = n0 + wc * 64;
  float bv[4];
#pragma unroll
  for (int j = 0; j < 4; ++j) bv[j] = bias[nc + j * 16 + ln15];

  if constexpr (MODE == 0) {
#pragma unroll
    for (int i = 0; i < 4; ++i) {
      const int m = m0 + wr * 64 + i * 16 + q4 * 4;
#pragma unroll
      for (int j = 0; j < 4; ++j)
#pragma unroll
        for (int r = 0; r < 4; ++r)
          out32[(size_t)(m + r) * N + nc + j * 16 + ln15] = acc[i][j][r] + bv[j];
    }
  } else {
    const int s = nc >> 10;          // 0=q 1=k 2=v
    const int h = (nc >> 6) & 15;    // head
    if (s == 2) {
      // V: plain f16, transposed [B,H,HD,L]
#pragma unroll
      for (int i = 0; i < 4; ++i) {
        const int m = m0 + wr * 64 + i * 16 + q4 * 4;
        const int b = m >> 11, l0 = m & (NL - 1);
#pragma unroll
        for (int j = 0; j < 4; ++j) {
          half4v pv;
#pragma unroll
          for (int r = 0; r < 4; ++r) pv[r] = (f16)(acc[i][j][r] + bv[j]);
          *(half4v*)&vth[(size_t)((b * NH + h) * NHD + j * 16 + ln15) * NL + l0] = pv;
        }
      }
    } else {
      const float* nw = (s == 0) ? qw : kw;
      f16* dh = (s == 0) ? qh : kh;
      f16* dl = (s == 0) ? ql : kl;
      // fold attention scale 1/8 and log2(e) into q
      const float qsc = (s == 0) ? 0.125f * 1.4426950408889634f : 1.0f;
      float wn[4];
#pragma unroll
      for (int j = 0; j < 4; ++j) wn[j] = nw[j * 16 + ln15];
#pragma unroll
      for (int i = 0; i < 4; ++i) {
        const int m = m0 + wr * 64 + i * 16 + q4 * 4;
        const int b = m >> 11, l0 = m & (NL - 1);
        float vv[4][4];
        float ss[4] = {0.f, 0.f, 0.f, 0.f};
#pragma unroll
        for (int j = 0; j < 4; ++j)
#pragma unroll
          for (int r = 0; r < 4; ++r) {
            vv[j][r] = acc[i][j][r] + bv[j];
            ss[r] += vv[j][r] * vv[j][r];
          }
#pragma unroll
        for (int r = 0; r < 4; ++r) {
          ss[r] += __shfl_xor(ss[r], 1);
          ss[r] += __shfl_xor(ss[r], 2);
          ss[r] += __shfl_xor(ss[r], 4);
          ss[r] += __shfl_xor(ss[r], 8);
          ss[r] = rsqrtf(ss[r] * (1.0f / 64.0f) + 1e-6f);
        }
#pragma unroll
        for (int j = 0; j < 4; ++j)
#pragma unroll
          for (int r = 0; r < 4; ++r) vv[j][r] *= ss[r] * wn[j];
        // rope: pair (hd, hd+32) = (j, j+2), angle index = jj*16+ln15
#pragma unroll
        for (int jj = 0; jj < 2; ++jj)
#pragma unroll
          for (int r = 0; r < 4; ++r) {
            const int l = l0 + r;
            const float c = tbl[l * 32 + jj * 16 + ln15];
            const float sn = tbl[65536 + l * 32 + jj * 16 + ln15];
            const float t1 = vv[jj][r], t2 = vv[jj + 2][r];
            vv[jj][r] = t1 * c - t2 * sn;
            vv[jj + 2][r] = t1 * sn + t2 * c;
          }
#pragma unroll
        for (int j = 0; j < 4; ++j)
#pragma unroll
          for (int r = 0; r < 4; ++r) {
            const float val = vv[j][r] * qsc;
            const f16 hv = (f16)val;
            const size_t di = (size_t)((b * NH + h) * NL + l0 + r) * NHD + j * 16 + ln15;
            dh[di] = hv;
            dl[di] = (f16)(val - (float)hv);
          }
      }
    }
  }
}

// ---------------------------------------------------------------------------
// Flash attention, swapped QK^T (S^T = K·Q^T) so each lane owns one q-row's
// S slice: row-reduce = local + 2 shuffles; per-lane scalar m/l/alpha.
// P transposed back to B-frag layout via packed b64 LDS writes / b128 reads
// (stride-72 rows: conflict-free). Defer-max (THR=8, log2 domain).
// O^T = V^T·P^T accumulated in registers; epilogue writes split O [B*L][D].
// ---------------------------------------------------------------------------
__global__ __launch_bounds__(256) void flash_mfma(
    const f16* __restrict__ qh, const f16* __restrict__ ql,
    const f16* __restrict__ kh, const f16* __restrict__ kl,
    const f16* __restrict__ vth, f16* __restrict__ Oh, f16* __restrict__ Ol) {
  __shared__ f16 KH[4096], KL[4096], VT[4096];
  __shared__ f16 Pl[4][16][72];  // per-wave P slice, row stride 144 B
  const int tid = threadIdx.x;
  const int ln = tid & 63, wv = tid >> 6;
  const int ln15 = ln & 15, q4 = ln >> 4;

  // head-major XCD swizzle: each XCD gets 8 whole heads
  const int flat = blockIdx.x;  // 1024
  const int swz = (flat & 7) * 128 + (flat >> 3);
  const int head = swz >> 4;  // b*16+h
  const int qt = swz & 15;
  const int b = head >> 4, h = head & 15;
  const int q0 = qt * 128 + wv * 32;
  const size_t hbase = (size_t)head * NL * NHD;

  // Q fragments (also serve as MFMA B-operand: same per-lane data)
  half8v qfh[2][2], qfl[2][2];
#pragma unroll
  for (int rf = 0; rf < 2; ++rf)
#pragma unroll
    for (int kb = 0; kb < 2; ++kb) {
      const size_t off = hbase + (size_t)(q0 + rf * 16 + ln15) * NHD + kb * 32 + q4 * 8;
      qfh[rf][kb] = *(const half8v*)&qh[off];
      qfl[rf][kb] = *(const half8v*)&ql[off];
    }

  f32x4 o_[4][2];  // O^T frag (df, rf): lane holds O[q=rf*16+ln15][d=df*16+q4*4+r]
  float m_[2], l_[2];
#pragma unroll
  for (int df = 0; df < 4; ++df)
#pragma unroll
    for (int rf = 0; rf < 2; ++rf) o_[df][rf] = (f32x4){0.f, 0.f, 0.f, 0.f};
  m_[0] = m_[1] = -INFINITY;
  l_[0] = l_[1] = 0.f;

  for (int kt = 0; kt < NL / 64; ++kt) {
    const int kv0 = kt * 64;
    // stage K hi/lo + V^T: 24 frags, 6 per wave
#pragma unroll
    for (int t = 0; t < 6; ++t) {
      const int f = wv * 6 + t;
      if (f < 8) {
        gload16(kh + hbase + (size_t)(kv0 + (f >> 1) * 16 + ln15) * NHD + (f & 1) * 32 + q4 * 8,
                &KH[f * 512]);
      } else if (f < 16) {
        const int g = f - 8;
        gload16(kl + hbase + (size_t)(kv0 + (g >> 1) * 16 + ln15) * NHD + (g & 1) * 32 + q4 * 8,
                &KL[g * 512]);
      } else {
        const int g = f - 16;
        gload16(vth + (size_t)(head * NHD + (g >> 1) * 16 + ln15) * NL + kv0 + (g & 1) * 32 + q4 * 8,
                &VT[g * 512]);
      }
    }
    __syncthreads();

    // S^T = Kh·Qh + Kl·Qh + Kh·Ql  (C-frag: row=kv, col=q)
    f32x4 s_[2][4];
#pragma unroll
    for (int rf = 0; rf < 2; ++rf)
#pragma unroll
      for (int cb = 0; cb < 4; ++cb) s_[rf][cb] = (f32x4){0.f, 0.f, 0.f, 0.f};
#pragma unroll
    for (int cb = 0; cb < 4; ++cb) {
      const half8v kh0 = *(half8v*)&KH[(cb * 2 + 0) * 512 + ln * 8];
      const half8v kh1 = *(half8v*)&KH[(cb * 2 + 1) * 512 + ln * 8];
      const half8v kl0 = *(half8v*)&KL[(cb * 2 + 0) * 512 + ln * 8];
      const half8v kl1 = *(half8v*)&KL[(cb * 2 + 1) * 512 + ln * 8];
#pragma unroll
      for (int rf = 0; rf < 2; ++rf) {
        f32x4 t = s_[rf][cb];
        t = MFMA16(kh0, qfh[rf][0], t);
        t = MFMA16(kh1, qfh[rf][1], t);
        t = MFMA16(kl0, qfh[rf][0], t);
        t = MFMA16(kl1, qfh[rf][1], t);
        t = MFMA16(kh0, qfl[rf][0], t);
        t = MFMA16(kh1, qfl[rf][1], t);
        s_[rf][cb] = t;
      }
    }

    // per-rf: in-register online softmax + packed-P round trip + PV
#pragma unroll
    for (int rf = 0; rf < 2; ++rf) {
      float pmax = -INFINITY;
#pragma unroll
      for (int cb = 0; cb < 4; ++cb)
#pragma unroll
        for (int r = 0; r < 4; ++r) pmax = fmaxf(pmax, s_[rf][cb][r]);
      pmax = fmaxf(pmax, __shfl_xor(pmax, 16));
      pmax = fmaxf(pmax, __shfl_xor(pmax, 32));
      if (!__all(pmax - m_[rf] <= 8.0f)) {  // defer-max: skip rescale usually
        const float mn = fmaxf(m_[rf], pmax);
        const float al = exp2f(m_[rf] - mn);
        m_[rf] = mn;
        l_[rf] *= al;
#pragma unroll
        for (int df = 0; df < 4; ++df) o_[df][rf] *= al;
      }
      float rs = 0.f;
#pragma unroll
      for (int cb = 0; cb < 4; ++cb) {
        half4v pk;
#pragma unroll
        for (int r = 0; r < 4; ++r) {
          const float p = exp2f(s_[rf][cb][r] - m_[rf]);
          rs += p;
          pk[r] = (f16)p;
        }
        *(half4v*)&Pl[wv][ln15][cb * 16 + q4 * 4] = pk;  // P[q=ln15][kv]
      }
      rs += __shfl_xor(rs, 16);
      rs += __shfl_xor(rs, 32);
      l_[rf] += rs;

      // O^T += V^T · P^T
#pragma unroll
      for (int ks = 0; ks < 2; ++ks) {
        const half8v pb = *(half8v*)&Pl[wv][ln15][ks * 32 + q4 * 8];
#pragma unroll
        for (int df = 0; df < 4; ++df) {
          const half8v vb = *(half8v*)&VT[(df * 2 + ks) * 512 + ln * 8];
          o_[df][rf] = MFMA16(vb, pb, o_[df][rf]);
        }
      }
    }
    __syncthreads();
  }

  // epilogue: normalize, split, write O [B*L][D]
#pragma unroll
  for (int rf = 0; rf < 2; ++rf) {
    const float invl = 1.0f / l_[rf];
    const int q = q0 + rf * 16 + ln15;
    const size_t rowb = (size_t)(b * NL + q) * ND + h * 64;
#pragma unroll
    for (int df = 0; df < 4; ++df) {
      half4v oh_, ol_;
#pragma unroll
      for (int r = 0; r < 4; ++r) {
        const float val = o_[df][rf][r] * invl;
        const f16 hv = (f16)val;
        oh_[r] = hv;
        ol_[r] = (f16)(val - (float)hv);
      }
      *(half4v*)&Oh[rowb + df * 16 + q4 * 4] = oh_;
      *(half4v*)&Ol[rowb + df * 16 + q4 * 4] = ol_;
    }
  }
}

// ---------------------------------------------------------------------------
extern "C" void kernel_launch(void* const* d_in, const int* in_sizes, int n_in,
                              void* d_out, int out_size, void* d_ws,
                              size_t ws_size, hipStream_t stream) {
  const float* x = (const float*)d_in[0];
  const float* Wqkv = (const float*)d_in[1];
  const float* bqkv = (const float*)d_in[2];
  const float* qn_w = (const float*)d_in[3];
  const float* kn_w = (const float*)d_in[4];
  const float* Wout = (const float*)d_in[5];
  const float* bout = (const float*)d_in[6];
  float* out = (float*)d_out;

  char* wsb = (char*)d_ws;
  // [0,80): qh|ql|kh|kl|vth (16 MiB each). [80,80.5): rope table.
  // [81,93) WqT h/l, [93,125) xh/xl  (dead after gemm1)
  // [81,113) Oh/Ol (flash output), [113,117) WoT h/l (written after gemm1).
  f16* qh = (f16*)(wsb);
  f16* ql = (f16*)(wsb + (16u << 20));
  f16* kh = (f16*)(wsb + (32u << 20));
  f16* kl = (f16*)(wsb + (48u << 20));
  f16* vth = (f16*)(wsb + (64u << 20));
  float* tbl = (float*)(wsb + (80u << 20));
  f16* WqTh = (f16*)(wsb + (81u << 20));
  f16* WqTl = (f16*)(wsb + (87u << 20));
  f16* xh = (f16*)(wsb + (93u << 20));
  f16* xl = (f16*)(wsb + (109u << 20));
  f16* Oh = (f16*)(wsb + (81u << 20));
  f16* Ol = (f16*)(wsb + (97u << 20));
  f16* WoTh = (f16*)(wsb + (113u << 20));
  f16* WoTl = (f16*)(wsb + (115u << 20));

  sctable<<<256, 256, 0, stream>>>(tbl);
  transplit<<<dim3(48, 16), 256, 0, stream>>>(Wqkv, WqTh, WqTl, 3 * ND);
  presplit<<<8192, 256, 0, stream>>>(x, xh, xl);

  gemm_split<3 * ND, 1><<<dim3(24, 64), 256, 0, stream>>>(
      xh, xl, WqTh, WqTl, bqkv, nullptr, qh, ql, kh, kl, vth, qn_w, kn_w, tbl);

  transplit<<<dim3(16, 16), 256, 0, stream>>>(Wout, WoTh, WoTl, ND);

  flash_mfma<<<1024, 256, 0, stream>>>(qh, ql, kh, kl, vth, Oh, Ol);

  gemm_split<ND, 0><<<dim3(8, 64), 256, 0, stream>>>(
      Oh, Ol, WoTh, WoTl, bout, out, nullptr, nullptr, nullptr, nullptr,
      nullptr, nullptr, nullptr, nullptr);
}